// Round 8
// baseline (10645.406 us; speedup 1.0000x reference)
//
#include <hip/hip_runtime.h>
#include <math.h>

#define S_LEN 4096
#define NTAG 20
#define TAG_STOP 19
#define NEGV -10000.0f

// ---------------- workspace layout (bytes) ----------------
// [0,256)          uint ready[64]         (per-64-pos pre-tile completion counters, -> 32)
// [4096,20480)     ull h_pub[2][2][512]   (dir, parity, unit) packed {seq32|h32}
// [65536, +64MB)   float pre[4096][4096]  (pos, row; rows 0..2047 fwd, 2048..4095 bwd)
// then             float hs[2][4096][512]
// then             float feats[4096][20]
// then             u8 bptr[4096*20]

__global__ void init_ws(unsigned int* ready, unsigned long long* hpub) {
    int i = blockIdx.x * 256 + threadIdx.x;
    if (i < 64) ready[i] = 0u;
    if (i < 2048) hpub[i] = 0ull;
}

__device__ __forceinline__ float sigm(float x) { return 1.0f / (1.0f + expf(-x)); }

__device__ __forceinline__ unsigned long long agent_ld(const unsigned long long* p) {
    return __hip_atomic_load(p, __ATOMIC_RELAXED, __HIP_MEMORY_SCOPE_AGENT);
}

__device__ __forceinline__ void tile_wait(const unsigned int* ready, unsigned int& rdy_tile, int t) {
    if ((unsigned int)t != rdy_tile) {
        while (__hip_atomic_load(&ready[t], __ATOMIC_ACQUIRE, __HIP_MEMORY_SCOPE_AGENT) < 32u)
            __builtin_amdgcn_s_sleep(4);
        rdy_tile = (unsigned int)t;
    }
}

// ---------------- fused kernel: blocks 0..31 = BiLSTM, blocks 32..2079 = pre-GEMM ----------------
// GEMM role: as R6 (write-through pre + ready[] release counters, bm from both ends).
// LSTM role changes vs R6: the 32 own-lanes (which never poll) now carry the
// pre-prefetch (triple-buffered pf_lds, slot s%3) and the hs store (1-step
// delayed, value via the own-unit LDS slot). Gate lanes' per-step VMEM shrinks
// to {1 poll load, 1 pub store}, so their poll test's vmcnt(0) no longer waits
// on HBM-latency pre loads / hs store acks. Bit-identical arithmetic.
__launch_bounds__(512, 2)
__global__ void fused_kernel(const int* __restrict__ sent, const float* __restrict__ embed,
                             const float* __restrict__ wf, const float* __restrict__ wb,
                             const float* __restrict__ bihf, const float* __restrict__ bhhf,
                             const float* __restrict__ bihb, const float* __restrict__ bhhb,
                             float* __restrict__ pre,
                             const float* __restrict__ w_hh_f, const float* __restrict__ w_hh_b,
                             const float* __restrict__ h0, const float* __restrict__ c0,
                             float* __restrict__ hs, unsigned long long* __restrict__ h_pub,
                             unsigned int* __restrict__ ready)
{
    __shared__ float As[16][68];
    __shared__ float Bs[16][136];
    __shared__ int   srow[64];
    __shared__ float buf[2][576];
    __shared__ float pf_lds[3][32][4];
    const int tid = threadIdx.x;

    if (blockIdx.x >= 32) {
        // ================= GEMM role =================
        const int gq = blockIdx.x - 32;
        const int q  = gq >> 5;
        const int bn = gq & 31;
        const int bm = (q & 1) ? (63 - (q >> 1)) : (q >> 1);
        const int pos0 = bm * 64, row0 = bn * 128;
        if (tid < 64) srow[tid] = sent[pos0 + tid];
        __syncthreads();

        const int ty = tid >> 5, tx = tid & 31;
        float acc[4][4];
        #pragma unroll
        for (int m = 0; m < 4; ++m)
            #pragma unroll
            for (int n = 0; n < 4; ++n) acc[m][n] = 0.f;

        for (int kt = 0; kt < 1024; kt += 16) {
            if (tid < 256) {   // A tile: 64 pos x 16 k
                int m = tid >> 2, kc = (tid & 3) * 4;
                float4 v = *(const float4*)(embed + (size_t)srow[m] * 1024 + kt + kc);
                As[kc+0][m] = v.x; As[kc+1][m] = v.y; As[kc+2][m] = v.z; As[kc+3][m] = v.w;
            }
            {   // B tile: 128 rows x 16 k
                int n = tid >> 2, kc = (tid & 3) * 4;
                int grow = row0 + n;
                const float* wsrc = (grow < 2048) ? (wf + (size_t)grow * 1024)
                                                  : (wb + (size_t)(grow - 2048) * 1024);
                float4 v = *(const float4*)(wsrc + kt + kc);
                Bs[kc+0][n] = v.x; Bs[kc+1][n] = v.y; Bs[kc+2][n] = v.z; Bs[kc+3][n] = v.w;
            }
            __syncthreads();
            #pragma unroll
            for (int kk = 0; kk < 16; ++kk) {
                float4 av = *(const float4*)&As[kk][ty * 4];
                float4 bv = *(const float4*)&Bs[kk][tx * 4];
                float a[4] = {av.x, av.y, av.z, av.w};
                float b[4] = {bv.x, bv.y, bv.z, bv.w};
                #pragma unroll
                for (int m = 0; m < 4; ++m)
                    #pragma unroll
                    for (int n = 0; n < 4; ++n) acc[m][n] += a[m] * b[n];
            }
            __syncthreads();
        }
        #pragma unroll
        for (int m = 0; m < 4; ++m) {
            int pos = pos0 + ty * 4 + m;
            #pragma unroll
            for (int n = 0; n < 4; ++n) {
                int grow = row0 + tx * 4 + n;
                float bias = (grow < 2048) ? (bihf[grow] + bhhf[grow])
                                           : (bihb[grow - 2048] + bhhb[grow - 2048]);
                __hip_atomic_store(&pre[(size_t)pos * 4096 + grow], acc[m][n] + bias,
                                   __ATOMIC_RELAXED, __HIP_MEMORY_SCOPE_AGENT);
            }
        }
        __syncthreads();   // vmcnt(0) drain: all tile stores at coherence point
        if (tid == 0)
            __hip_atomic_fetch_add(&ready[bm], 1u, __ATOMIC_RELEASE, __HIP_MEMORY_SCOPE_AGENT);
        return;
    }

    // ================= LSTM role =================
    const int dir  = blockIdx.x >> 4;
    const int wg   = blockIdx.x & 15;
    const int wv   = tid >> 6;
    const int lane = tid & 63;
    const int rg   = lane >> 4;
    const int ks   = lane & 15;
    const int j    = wg * 32 + wv * 4 + rg;        // this lane-group's global unit
    const int lj   = wv * 4 + rg;                  // local unit index of lane-group
    const float* w_hh = dir ? w_hh_b : w_hh_f;

    // ---- weights: 4 gate rows (g*512+j) x 32 k (ks slice), 128 f32 ----
    float wr0[32], wr1[32], wr2[32], wr3[32];
    {
        const float* wbase = w_hh + (size_t)j * 512 + ks * 32;
        #pragma unroll
        for (int qq = 0; qq < 8; ++qq) {
            float4 v0 = *(const float4*)(wbase + 0 * 262144 + qq * 4);
            wr0[qq*4+0] = v0.x; wr0[qq*4+1] = v0.y; wr0[qq*4+2] = v0.z; wr0[qq*4+3] = v0.w;
            float4 v1 = *(const float4*)(wbase + 1 * 262144 + qq * 4);
            wr1[qq*4+0] = v1.x; wr1[qq*4+1] = v1.y; wr1[qq*4+2] = v1.z; wr1[qq*4+3] = v1.w;
            float4 v2 = *(const float4*)(wbase + 2 * 262144 + qq * 4);
            wr2[qq*4+0] = v2.x; wr2[qq*4+1] = v2.y; wr2[qq*4+2] = v2.z; wr2[qq*4+3] = v2.w;
            float4 v3 = *(const float4*)(wbase + 3 * 262144 + qq * 4);
            wr3[qq*4+0] = v3.x; wr3[qq*4+1] = v3.y; wr3[qq*4+2] = v3.z; wr3[qq*4+3] = v3.w;
        }
    }

    const bool gate = (ks == 0);
    const bool ownL = ((tid >> 5) == wg);          // own-lane: su==tid is a block-owned unit
    const int  lj2  = tid - wg * 32;               // own-lane's local unit (valid iff ownL)
    const int  su   = tid;                         // unit staged by this thread
    const bool own  = ownL;                        // own units come via LDS fast path
    const int  sidx = su + ((su >> 5) << 2);       // padded LDS index
    unsigned long long* pub = h_pub + dir * 1024;

    unsigned int rdy_tile = 0xffffffffu;
    float c_reg = 0.f;
    if (gate) c_reg = c0[dir * 512 + j];

    // ---- prologue: own lanes fill pf_lds slots 0 (s=0) and 1 (s=1) ----
    if (ownL) {
        const int p0 = dir ? (S_LEN - 1) : 0;
        const int p1 = dir ? (S_LEN - 2) : 1;
        tile_wait(ready, rdy_tile, p0 >> 6);
        const float* pb0 = pre + (size_t)p0 * 4096 + dir * 2048 + tid;
        pf_lds[0][lj2][0] = pb0[0]; pf_lds[0][lj2][1] = pb0[512];
        pf_lds[0][lj2][2] = pb0[1024]; pf_lds[0][lj2][3] = pb0[1536];
        tile_wait(ready, rdy_tile, p1 >> 6);
        const float* pb1 = pre + (size_t)p1 * 4096 + dir * 2048 + tid;
        pf_lds[1][lj2][0] = pb1[0]; pf_lds[1][lj2][1] = pb1[512];
        pf_lds[1][lj2][2] = pb1[1024]; pf_lds[1][lj2][3] = pb1[1536];
    }

    for (int s = 0; s < S_LEN; ++s) {
        const int P = s & 1;
        // ---- stage h_{s-1} into buf[P]: one 8B data-is-flag poll per thread ----
        if (s == 0) {
            buf[0][sidx] = h0[dir * 512 + su];
        } else if (!own) {
            const unsigned int expect = (unsigned int)s;
            const unsigned long long* p = &pub[P * 512 + su];
            unsigned long long u = agent_ld(p);
            while ((unsigned int)(u >> 32) < expect) u = agent_ld(p);
            buf[P][sidx] = __uint_as_float((unsigned int)u);
        }
        __syncthreads();   // the only barrier per step (also publishes prologue pf_lds at s=0)

        // ---- gate: early pf read (hidden under matvec) ----
        float4 pf4 = make_float4(0.f, 0.f, 0.f, 0.f);
        if (gate) pf4 = *(const float4*)&pf_lds[s % 3][lj][0];

        // ---- own lanes: issue pre prefetch for step s+2 (returns drained by pf_lds write) ----
        float pr0 = 0.f, pr1 = 0.f, pr2 = 0.f, pr3 = 0.f;
        const bool doPre = ownL && (s + 2 < S_LEN);
        if (doPre) {
            const int pp = dir ? (S_LEN - 3 - s) : (s + 2);
            tile_wait(ready, rdy_tile, pp >> 6);
            const float* pb = pre + (size_t)pp * 4096 + dir * 2048 + tid;
            pr0 = pb[0]; pr1 = pb[512]; pr2 = pb[1024]; pr3 = pb[1536];
        }

        // ---- matvec: 4 gate rows x 32 k per lane, weights register-resident ----
        float a0 = 0.f, a1 = 0.f, a2 = 0.f, a3 = 0.f;
        const float* hp = &buf[P][ks * 36];
        #pragma unroll
        for (int q = 0; q < 8; ++q) {
            float4 h4 = ((const float4*)hp)[q];
            a0 += wr0[q*4+0]*h4.x + wr0[q*4+1]*h4.y + wr0[q*4+2]*h4.z + wr0[q*4+3]*h4.w;
            a1 += wr1[q*4+0]*h4.x + wr1[q*4+1]*h4.y + wr1[q*4+2]*h4.z + wr1[q*4+3]*h4.w;
            a2 += wr2[q*4+0]*h4.x + wr2[q*4+1]*h4.y + wr2[q*4+2]*h4.z + wr2[q*4+3]*h4.w;
            a3 += wr3[q*4+0]*h4.x + wr3[q*4+1]*h4.y + wr3[q*4+2]*h4.z + wr3[q*4+3]*h4.w;
        }
        // ---- 16-lane butterfly reduce over k-slices ----
        a0 += __shfl_xor(a0, 1); a0 += __shfl_xor(a0, 2); a0 += __shfl_xor(a0, 4); a0 += __shfl_xor(a0, 8);
        a1 += __shfl_xor(a1, 1); a1 += __shfl_xor(a1, 2); a1 += __shfl_xor(a1, 4); a1 += __shfl_xor(a1, 8);
        a2 += __shfl_xor(a2, 1); a2 += __shfl_xor(a2, 2); a2 += __shfl_xor(a2, 4); a2 += __shfl_xor(a2, 8);
        a3 += __shfl_xor(a3, 1); a3 += __shfl_xor(a3, 2); a3 += __shfl_xor(a3, 4); a3 += __shfl_xor(a3, 8);

        // ---- own lanes: 1-step-delayed hs store + pf_lds rotate ----
        if (ownL) {
            if (s > 0) {
                float hv = buf[P][tid + 4 * wg];   // h_{s-1}, written by gate lane at step s-1
                const int posm = dir ? (S_LEN - s) : (s - 1);
                hs[((size_t)dir * S_LEN + posm) * 512 + tid] = hv;
            }
            if (doPre) {
                float* d = &pf_lds[(s + 2) % 3][lj2][0];
                d[0] = pr0; d[1] = pr1; d[2] = pr2; d[3] = pr3;
            }
        }

        // ---- gates + publish (lane ks==0 of each 16-group: 1 unit) ----
        if (gate) {
            float gi = a0 + pf4.x, gf = a1 + pf4.y, gg = a2 + pf4.z, go = a3 + pf4.w;
            float cn = sigm(gf) * c_reg + sigm(gi) * tanhf(gg);
            float hN = sigm(go) * tanhf(cn);
            c_reg = cn;
            unsigned long long uv = ((unsigned long long)(unsigned int)(s + 1) << 32)
                                  | (unsigned long long)__float_as_uint(hN);
            __hip_atomic_store(&pub[(P ^ 1) * 512 + j], uv,
                               __ATOMIC_RELAXED, __HIP_MEMORY_SCOPE_AGENT);
            buf[P ^ 1][j + 4 * wg] = hN;           // own-unit fast path (next parity)
        }
    }
    __syncthreads();
    if (ownL) {   // final hs store: h_{4095} sits in buf[0] (P=1 at s=4095 -> P^1=0)
        float hv = buf[0][tid + 4 * wg];
        const int posm = dir ? 0 : (S_LEN - 1);
        hs[((size_t)dir * S_LEN + posm) * 512 + tid] = hv;
    }
}

// ---------------- kernel C: feats = concat(hf,hb) @ w_out^T + b_out ----------------
__launch_bounds__(256)
__global__ void feats_kernel(const float* __restrict__ hs, const float* __restrict__ w_out,
                             const float* __restrict__ b_out, float* __restrict__ feats)
{
    const int pos = blockIdx.x;
    const int tid = threadIdx.x;
    __shared__ float hbuf[1024];
    __shared__ float red[160];
    {
        const float* hf = hs + (size_t)pos * 512;
        const float* hb = hs + ((size_t)S_LEN + pos) * 512;
        if (tid < 128) *(float4*)&hbuf[tid * 4]           = *(const float4*)&hf[tid * 4];
        else           *(float4*)&hbuf[512 + (tid-128)*4] = *(const float4*)&hb[(tid - 128) * 4];
    }
    __syncthreads();
    if (tid < 160) {
        int tag = tid >> 3, part = tid & 7;
        const float* wrow = w_out + (size_t)tag * 1024 + part * 128;
        const float* hrow = hbuf + part * 128;
        float sum = 0.f;
        #pragma unroll
        for (int q = 0; q < 32; ++q) {
            float4 a = ((const float4*)hrow)[q];
            float4 b = ((const float4*)wrow)[q];
            sum += a.x*b.x + a.y*b.y + a.z*b.z + a.w*b.w;
        }
        red[tid] = sum;
    }
    __syncthreads();
    if (tid < NTAG) {
        float sum = b_out[tid];
        #pragma unroll
        for (int pq = 0; pq < 8; ++pq) sum += red[tid * 8 + pq];
        feats[(size_t)pos * NTAG + tid] = sum;
    }
}

// ---------------- kernel D: Viterbi forward (tree argmax) + 32-chunk backtrace ----------------
__launch_bounds__(1024)
__global__ void viterbi_kernel(const float* __restrict__ feats, const float* __restrict__ trans,
                               unsigned char* __restrict__ bptr, float* __restrict__ out)
{
    __shared__ float feat_lds[64 * NTAG];
    __shared__ int sh_best;
    __shared__ unsigned char Mmap[32][NTAG];
    __shared__ unsigned char entry_s[32];
    const int tid = threadIdx.x;

    if (tid < 64) {   // wave 0: sequential forward pass
        const int lane = tid;
        const int i = (lane < NTAG) ? lane : (NTAG - 1);
        float trow[NTAG];
        #pragma unroll
        for (int jj = 0; jj < NTAG; ++jj) trow[jj] = trans[i * NTAG + jj];
        float fv[NTAG];
        #pragma unroll
        for (int jj = 0; jj < NTAG; ++jj) fv[jj] = (jj == 18) ? 0.f : NEGV;

        for (int blk = 0; blk < 64; ++blk) {
            #pragma unroll
            for (int q = 0; q < 20; ++q)
                feat_lds[q * 64 + lane] = feats[blk * 1280 + q * 64 + lane];
            for (int ss = 0; ss < 64; ++ss) {
                int s = blk * 64 + ss;
                // tree argmax over 20 candidates (first-max tie rule: '<' keeps lower idx)
                float cand[NTAG]; int idx[NTAG];
                #pragma unroll
                for (int jj = 0; jj < NTAG; ++jj) { cand[jj] = fv[jj] + trow[jj]; idx[jj] = jj; }
                #pragma unroll
                for (int st = 1; st < NTAG; st <<= 1)
                    #pragma unroll
                    for (int j0 = 0; j0 + st < NTAG; j0 += 2 * st)
                        if (cand[j0] < cand[j0 + st]) { cand[j0] = cand[j0 + st]; idx[j0] = idx[j0 + st]; }
                float fnew = cand[0] + feat_lds[ss * NTAG + i];
                if (lane < NTAG) bptr[s * NTAG + lane] = (unsigned char)idx[0];
                #pragma unroll
                for (int jj = 0; jj < NTAG; ++jj) fv[jj] = __shfl(fnew, jj);
            }
        }
        if (lane == 0) {
            float best = -1e30f; int bt = 0;
            for (int jj = 0; jj < NTAG; ++jj) {
                float t2 = fv[jj] + trans[TAG_STOP * NTAG + jj];
                if (t2 > best) { best = t2; bt = jj; }
            }
            out[0] = best;
            sh_best = bt;
        }
    }
    __syncthreads();
    // phase 1: per-chunk entry-tag -> chunk-start-tag maps (32 chunks x 20 entries)
    if (tid < 32 * NTAG) {
        int c = tid / NTAG, e = tid % NTAG;
        int tag = e;
        for (int t = (c + 1) * 128 - 1; t >= c * 128; --t) tag = bptr[t * NTAG + tag];
        Mmap[c][e] = (unsigned char)tag;
    }
    __syncthreads();
    // phase 2: serial chain through 32 chunk maps
    if (tid == 0) {
        int e = sh_best;
        entry_s[31] = (unsigned char)e;
        for (int c = 31; c >= 1; --c) { e = Mmap[c][e]; entry_s[c - 1] = (unsigned char)e; }
    }
    __syncthreads();
    // phase 3: re-walk each chunk writing the path
    if (tid < 32) {
        int c = tid;
        int tag = entry_s[c];
        out[1 + (c + 1) * 128 - 1] = (float)tag;
        for (int t = (c + 1) * 128 - 1; t > c * 128; --t) {
            tag = bptr[t * NTAG + tag];
            out[1 + t - 1] = (float)tag;
        }
    }
}

extern "C" void kernel_launch(void* const* d_in, const int* in_sizes, int n_in,
                              void* d_out, int out_size, void* d_ws, size_t ws_size,
                              hipStream_t stream) {
    (void)in_sizes; (void)n_in; (void)out_size; (void)ws_size;
    const int*   sent  = (const int*)d_in[0];
    const float* embed = (const float*)d_in[1];
    const float* wihf  = (const float*)d_in[2];
    const float* whhf  = (const float*)d_in[3];
    const float* bihf  = (const float*)d_in[4];
    const float* bhhf  = (const float*)d_in[5];
    const float* wihb  = (const float*)d_in[6];
    const float* whhb  = (const float*)d_in[7];
    const float* bihb  = (const float*)d_in[8];
    const float* bhhb  = (const float*)d_in[9];
    const float* wout  = (const float*)d_in[10];
    const float* bout  = (const float*)d_in[11];
    const float* trans = (const float*)d_in[12];
    const float* h0    = (const float*)d_in[13];
    const float* c0    = (const float*)d_in[14];

    char* ws = (char*)d_ws;
    unsigned int* ready       = (unsigned int*)ws;
    unsigned long long* h_pub = (unsigned long long*)(ws + 4096);   // 16 KB
    float* pre   = (float*)(ws + 65536);
    float* hs    = (float*)(ws + 65536 + (size_t)4096 * 4096 * 4);
    float* feats = (float*)(ws + 65536 + (size_t)4096 * 4096 * 4 + (size_t)2 * 4096 * 512 * 4);
    unsigned char* bptr = (unsigned char*)(feats + (size_t)S_LEN * NTAG);
    float* out = (float*)d_out;

    hipLaunchKernelGGL(init_ws, dim3(8), dim3(256), 0, stream, ready, h_pub);
    hipLaunchKernelGGL(fused_kernel, dim3(32 + 2048), dim3(512), 0, stream,
                       sent, embed, wihf, wihb, bihf, bhhf, bihb, bhhb, pre,
                       whhf, whhb, h0, c0, hs, h_pub, ready);
    hipLaunchKernelGGL(feats_kernel, dim3(S_LEN), dim3(256), 0, stream,
                       hs, wout, bout, feats);
    hipLaunchKernelGGL(viterbi_kernel, dim3(1), dim3(1024), 0, stream,
                       feats, trans, bptr, out);
}